// Round 1
// baseline (3021.848 us; speedup 1.0000x reference)
//
#include <hip/hip_runtime.h>
#include <cstdint>
#include <cstddef>

// Problem constants
#define NP      2048        // patches
#define NN      100000      // memory nodes
#define DIM     256
#define RPB     64          // rows per block (k_attn)
#define NCH     8           // node chunks
#define NPC     (NN/NCH)    // 12500 nodes per chunk
#define TB      64          // node tile staged in LDS
#define INV_TAU 50.0f
#define THRESH  1e-12f
#define PSTR    260         // partial row stride (floats): [m, l, pad, pad, acc[256]]

// ---------------------------------------------------------------------------
// K1: streaming online-softmax attention partials.
// Block (rt, ch): rows rt*64..+63, nodes ch*12500..+12499.
// 256 threads: tr = tid>>4 owns 4 rows, tj = tid&15 owns 4 nodes (QK^T tile)
// and dims d = tj*16..+15 of the accumulator.
// ---------------------------------------------------------------------------
__global__ __launch_bounds__(256, 1)
void k_attn(const float* __restrict__ A, const float* __restrict__ B,
            float* __restrict__ part)
{
    __shared__ float Ast[DIM][68];   // A transposed: Ast[d][row]
    __shared__ float Bst[DIM][68];   // B tile transposed: Bst[d][node]

    const int rt   = blockIdx.x;
    const int ch   = blockIdx.y;
    const int row0 = rt * RPB;
    const int n0   = ch * NPC;
    const int n1   = n0 + NPC;
    const int tid  = (int)threadIdx.x;
    const int tr   = tid >> 4;       // 0..15
    const int tj   = tid & 15;       // 0..15
    const int lane = tid & 63;
    const int gbase = lane & 48;     // base of this 16-lane group within the wave

    // stage A transposed (once)
    for (int i = tid; i < RPB * (DIM / 4); i += 256) {
        int r  = i >> 6;             // 64 float4 per row
        int c4 = (i & 63) << 2;
        float4 v = *reinterpret_cast<const float4*>(&A[(size_t)(row0 + r) * DIM + c4]);
        Ast[c4 + 0][r] = v.x; Ast[c4 + 1][r] = v.y;
        Ast[c4 + 2][r] = v.z; Ast[c4 + 3][r] = v.w;
    }

    float m[4], l[4], acc[4][16];
#pragma unroll
    for (int i = 0; i < 4; ++i) {
        m[i] = -INFINITY; l[i] = 0.0f;
#pragma unroll
        for (int k = 0; k < 16; ++k) acc[i][k] = 0.0f;
    }

    for (int nb = n0; nb < n1; nb += TB) {
        __syncthreads();   // protects Bst re-write (and Ast staging on 1st iter)

        // stage B tile transposed
        for (int i = tid; i < TB * (DIM / 4); i += 256) {
            int j  = i >> 6;
            int c4 = (i & 63) << 2;
            float4 v = make_float4(0.f, 0.f, 0.f, 0.f);
            if (nb + j < n1)
                v = *reinterpret_cast<const float4*>(&B[(size_t)(nb + j) * DIM + c4]);
            Bst[c4 + 0][j] = v.x; Bst[c4 + 1][j] = v.y;
            Bst[c4 + 2][j] = v.z; Bst[c4 + 3][j] = v.w;
        }
        __syncthreads();

        // QK^T: 4x4 register tile
        float s[4][4];
#pragma unroll
        for (int i = 0; i < 4; ++i)
#pragma unroll
            for (int j = 0; j < 4; ++j) s[i][j] = 0.0f;

#pragma unroll 4
        for (int d = 0; d < DIM; ++d) {
            float4 av = *reinterpret_cast<const float4*>(&Ast[d][tr << 2]);
            float4 bv = *reinterpret_cast<const float4*>(&Bst[d][tj << 2]);
            s[0][0] += av.x * bv.x; s[0][1] += av.x * bv.y; s[0][2] += av.x * bv.z; s[0][3] += av.x * bv.w;
            s[1][0] += av.y * bv.x; s[1][1] += av.y * bv.y; s[1][2] += av.y * bv.z; s[1][3] += av.y * bv.w;
            s[2][0] += av.z * bv.x; s[2][1] += av.z * bv.y; s[2][2] += av.z * bv.z; s[2][3] += av.z * bv.w;
            s[3][0] += av.w * bv.x; s[3][1] += av.w * bv.y; s[3][2] += av.w * bv.z; s[3][3] += av.w * bv.w;
        }

        // mask invalid nodes (ragged last tile)
#pragma unroll
        for (int j = 0; j < 4; ++j) {
            if (nb + tj * 4 + j >= n1) {
                s[0][j] = -1e30f; s[1][j] = -1e30f; s[2][j] = -1e30f; s[3][j] = -1e30f;
            }
        }

        // online softmax update per row
#pragma unroll
        for (int i = 0; i < 4; ++i) {
            float tm = fmaxf(fmaxf(s[i][0], s[i][1]), fmaxf(s[i][2], s[i][3]));
            tm = fmaxf(tm, __shfl_xor(tm, 1));
            tm = fmaxf(tm, __shfl_xor(tm, 2));
            tm = fmaxf(tm, __shfl_xor(tm, 4));
            tm = fmaxf(tm, __shfl_xor(tm, 8));
            float newm = fmaxf(m[i], tm);
            float sc = __expf((m[i] - newm) * INV_TAU);   // -inf -> 0 on first tile
            m[i] = newm;

            float e0 = __expf((s[i][0] - newm) * INV_TAU);
            float e1 = __expf((s[i][1] - newm) * INV_TAU);
            float e2 = __expf((s[i][2] - newm) * INV_TAU);
            float e3 = __expf((s[i][3] - newm) * INV_TAU);
            float es = e0 + e1 + e2 + e3;
            es += __shfl_xor(es, 1);
            es += __shfl_xor(es, 2);
            es += __shfl_xor(es, 4);
            es += __shfl_xor(es, 8);
            l[i] = l[i] * sc + es;

#pragma unroll
            for (int k = 0; k < 16; ++k) acc[i][k] *= sc;

            // sparse PV: only significant weights contribute
            bool flag = (e0 > THRESH) | (e1 > THRESH) | (e2 > THRESH) | (e3 > THRESH);
            unsigned long long bal = __ballot(flag);
            unsigned int gm = (unsigned int)((bal >> gbase) & 0xFFFFull);
            if (gm) {
                for (int src = 0; src < 16; ++src) {
                    if (!((gm >> src) & 1u)) continue;
                    float f0 = __shfl(e0, gbase + src);
                    float f1 = __shfl(e1, gbase + src);
                    float f2 = __shfl(e2, gbase + src);
                    float f3 = __shfl(e3, gbase + src);
                    float fv[4] = { f0, f1, f2, f3 };
                    int jb = nb + src * 4;
#pragma unroll
                    for (int jj = 0; jj < 4; ++jj) {
                        if (fv[jj] > THRESH) {
                            const float* bp = &B[(size_t)(jb + jj) * DIM + tj * 16];
                            float4 b0 = *reinterpret_cast<const float4*>(bp + 0);
                            float4 b1 = *reinterpret_cast<const float4*>(bp + 4);
                            float4 b2 = *reinterpret_cast<const float4*>(bp + 8);
                            float4 b3 = *reinterpret_cast<const float4*>(bp + 12);
                            float w = fv[jj];
                            acc[i][0]  += w * b0.x; acc[i][1]  += w * b0.y; acc[i][2]  += w * b0.z; acc[i][3]  += w * b0.w;
                            acc[i][4]  += w * b1.x; acc[i][5]  += w * b1.y; acc[i][6]  += w * b1.z; acc[i][7]  += w * b1.w;
                            acc[i][8]  += w * b2.x; acc[i][9]  += w * b2.y; acc[i][10] += w * b2.z; acc[i][11] += w * b2.w;
                            acc[i][12] += w * b3.x; acc[i][13] += w * b3.y; acc[i][14] += w * b3.z; acc[i][15] += w * b3.w;
                        }
                    }
                }
            }
        }
    }

    // write partials
#pragma unroll
    for (int i = 0; i < 4; ++i) {
        int row = row0 + tr * 4 + i;
        float* pr = part + ((size_t)ch * NP + row) * PSTR;
        if (tj == 0) { pr[0] = m[i]; pr[1] = l[i]; }
        float4* pa = reinterpret_cast<float4*>(pr + 4 + tj * 16);
        pa[0] = make_float4(acc[i][0],  acc[i][1],  acc[i][2],  acc[i][3]);
        pa[1] = make_float4(acc[i][4],  acc[i][5],  acc[i][6],  acc[i][7]);
        pa[2] = make_float4(acc[i][8],  acc[i][9],  acc[i][10], acc[i][11]);
        pa[3] = make_float4(acc[i][12], acc[i][13], acc[i][14], acc[i][15]);
    }
}

// ---------------------------------------------------------------------------
// K2: combine chunk partials -> messages -> updated = l2norm(patch + msg).
// One wave per row; lane owns 4 dims. Also writes evidence[row] = max sim.
// ---------------------------------------------------------------------------
__global__ __launch_bounds__(256)
void k_combine(const float* __restrict__ A, const float* __restrict__ part,
               float* __restrict__ out, float* __restrict__ evidence)
{
    const int w    = (int)threadIdx.x >> 6;
    const int lane = (int)threadIdx.x & 63;
    const int row  = blockIdx.x * 4 + w;
    const int d0   = lane * 4;

    float mc[NCH];
    float M = -INFINITY;
#pragma unroll
    for (int c = 0; c < NCH; ++c) {
        mc[c] = part[((size_t)c * NP + row) * PSTR];
        M = fmaxf(M, mc[c]);
    }
    float L = 0.0f;
    float mx = 0.f, my = 0.f, mz = 0.f, mw = 0.f;
#pragma unroll
    for (int c = 0; c < NCH; ++c) {
        const float* pr = part + ((size_t)c * NP + row) * PSTR;
        float wc = __expf((mc[c] - M) * INV_TAU);
        L += wc * pr[1];
        float4 a = *reinterpret_cast<const float4*>(pr + 4 + d0);
        mx += wc * a.x; my += wc * a.y; mz += wc * a.z; mw += wc * a.w;
    }
    float inv = 1.0f / L;
    float4 p = *reinterpret_cast<const float4*>(&A[(size_t)row * DIM + d0]);
    float ux = p.x + mx * inv, uy = p.y + my * inv;
    float uz = p.z + mz * inv, uw = p.w + mw * inv;
    float ss = ux * ux + uy * uy + uz * uz + uw * uw;
#pragma unroll
    for (int o = 1; o < 64; o <<= 1) ss += __shfl_xor(ss, o);
    float n = sqrtf(ss);
    float r = 1.0f / fmaxf(n, 1e-12f);
    *reinterpret_cast<float4*>(&out[256 + (size_t)row * DIM + d0]) =
        make_float4(ux * r, uy * r, uz * r, uw * r);
    if (lane == 0) evidence[row] = M;
}

// ---------------------------------------------------------------------------
// K3a: max of evidence (softmax denominator cancels under final l2norm).
// ---------------------------------------------------------------------------
__global__ __launch_bounds__(256)
void k_evmax(const float* __restrict__ evidence, float* __restrict__ me)
{
    __shared__ float red[256];
    int tid = (int)threadIdx.x;
    float M = -INFINITY;
    for (int r = tid; r < NP; r += 256) M = fmaxf(M, evidence[r]);
    red[tid] = M; __syncthreads();
    for (int s = 128; s > 0; s >>= 1) {
        if (tid < s) red[tid] = fmaxf(red[tid], red[tid + s]);
        __syncthreads();
    }
    if (tid == 0) me[0] = red[0];
}

// ---------------------------------------------------------------------------
// K3b: partial evidence-weighted sums of `updated` (16 blocks x 128 rows).
// ---------------------------------------------------------------------------
__global__ __launch_bounds__(256)
void k_gpart(const float* __restrict__ evidence, const float* __restrict__ me,
             const float* __restrict__ out, float* __restrict__ gpart)
{
    __shared__ float wsh[128];
    int tid = (int)threadIdx.x;
    int r0  = blockIdx.x * 128;
    float Me = me[0];
    if (tid < 128) wsh[tid] = __expf((evidence[r0 + tid] - Me) * INV_TAU);
    __syncthreads();
    float g = 0.0f;
    for (int k = 0; k < 128; ++k)
        g += wsh[k] * out[256 + (size_t)(r0 + k) * DIM + tid];
    gpart[blockIdx.x * 256 + tid] = g;
}

// ---------------------------------------------------------------------------
// K3c: reduce partials, l2-normalize, write global feature to out[0..255].
// ---------------------------------------------------------------------------
__global__ __launch_bounds__(256)
void k_final(const float* __restrict__ gpart, float* __restrict__ out)
{
    __shared__ float red[256];
    int tid = (int)threadIdx.x;
    float g = 0.0f;
#pragma unroll
    for (int b = 0; b < 16; ++b) g += gpart[b * 256 + tid];
    red[tid] = g * g; __syncthreads();
    for (int s = 128; s > 0; s >>= 1) {
        if (tid < s) red[tid] += red[tid + s];
        __syncthreads();
    }
    float n = sqrtf(red[0]);
    float r = 1.0f / fmaxf(n, 1e-12f);
    out[tid] = g * r;
}

// ---------------------------------------------------------------------------
extern "C" void kernel_launch(void* const* d_in, const int* in_sizes, int n_in,
                              void* d_out, int out_size, void* d_ws, size_t ws_size,
                              hipStream_t stream)
{
    const float* A = (const float*)d_in[0];   // test_patches 2048x256 f32
    const float* B = (const float*)d_in[1];   // memory_nodes 100000x256 f32
    float* out = (float*)d_out;               // [256 global] + [2048x256 updated]
    float* ws  = (float*)d_ws;

    float* part     = ws;                                   // NCH*NP*PSTR floats (~17 MB)
    float* evidence = ws + (size_t)NCH * NP * PSTR;         // NP floats
    float* me       = evidence + NP;                        // 1 float (+pad)
    float* gpart    = me + 16;                              // 16*256 floats

    k_attn   <<<dim3(32, NCH), 256, 0, stream>>>(A, B, part);
    k_combine<<<NP / 4,        256, 0, stream>>>(A, part, out, evidence);
    k_evmax  <<<1,             256, 0, stream>>>(evidence, me);
    k_gpart  <<<16,            256, 0, stream>>>(evidence, me, out, gpart);
    k_final  <<<1,             256, 0, stream>>>(gpart, out);
}

// Round 3
// 1463.543 us; speedup vs baseline: 2.0647x; 2.0647x over previous
//
#include <hip/hip_runtime.h>
#include <cstdint>
#include <cstddef>

// Problem constants
#define NP      2048        // patches
#define NN      100000      // memory nodes
#define DIM     256
#define NCH     16          // node chunks
#define NPC     (NN/NCH)    // 6250 nodes per chunk
#define RPB     128         // rows per k_attn block (8 waves x 16 rows)
#define INV_TAU 50.0f
#define THRESH  1e-12f
#define PSTR    260         // partial row stride (floats): [m, l, pad, pad, acc[256]]

typedef __fp16 half8  __attribute__((ext_vector_type(8)));
typedef __fp16 half2v __attribute__((ext_vector_type(2)));
typedef float  floatx4 __attribute__((ext_vector_type(4)));

union H8 { half8 v8; half2v v2[4]; };

// f32x8 -> f16 hi (RTZ) + f16 lo (residual). Error per element ~2^-20 abs.
__device__ __forceinline__ void split8(const float4& a, const float4& b, H8& hi, H8& lo)
{
    half2v h0 = __builtin_amdgcn_cvt_pkrtz(a.x, a.y);
    half2v h1 = __builtin_amdgcn_cvt_pkrtz(a.z, a.w);
    half2v h2 = __builtin_amdgcn_cvt_pkrtz(b.x, b.y);
    half2v h3 = __builtin_amdgcn_cvt_pkrtz(b.z, b.w);
    half2v l0 = __builtin_amdgcn_cvt_pkrtz(a.x - (float)h0[0], a.y - (float)h0[1]);
    half2v l1 = __builtin_amdgcn_cvt_pkrtz(a.z - (float)h1[0], a.w - (float)h1[1]);
    half2v l2 = __builtin_amdgcn_cvt_pkrtz(b.x - (float)h2[0], b.y - (float)h2[1]);
    half2v l3 = __builtin_amdgcn_cvt_pkrtz(b.z - (float)h3[0], b.w - (float)h3[1]);
    hi.v2[0] = h0; hi.v2[1] = h1; hi.v2[2] = h2; hi.v2[3] = h3;
    lo.v2[0] = l0; lo.v2[1] = l1; lo.v2[2] = l2; lo.v2[3] = l3;
}

// ---------------------------------------------------------------------------
// K1: streaming online-softmax attention partials via split-f16 MFMA.
// Grid (16 rowblocks, 16 chunks); 512 threads = 8 waves; wave owns 16 rows.
// A-frags live in registers (all K). B-frags loaded straight from global in
// MFMA lane layout: lane l -> node (l&15), k-range 8*(l>>4) + 32*ks.
// S layout after MFMA (m89): col = lane&15 (node), row = 4*(lane>>4)+reg.
// No LDS, no barriers in the main loop.
// ---------------------------------------------------------------------------
__global__ __launch_bounds__(512, 2)
void k_attn(const float* __restrict__ A, const float* __restrict__ B,
            float* __restrict__ part)
{
    const int tid   = (int)threadIdx.x;
    const int w     = tid >> 6;          // wave 0..7
    const int lane  = tid & 63;
    const int col   = lane & 15;         // node-in-tile / A-row-in-subtile
    const int kg    = lane >> 4;         // 0..3 k-group
    const int gbase = lane & 48;
    const int row0  = blockIdx.x * RPB;  // block rows
    const int wrow0 = row0 + w * 16;     // this wave's rows
    const int ch    = blockIdx.y;
    const int n0    = ch * NPC;
    const int n1    = n0 + NPC;

    // Prologue: A-fragments (hi+lo) for all 8 K-steps into registers.
    H8 a_hi[8], a_lo[8];
    {
        const float* ap = A + (size_t)(wrow0 + col) * DIM + kg * 8;
#pragma unroll
        for (int ks = 0; ks < 8; ++ks) {
            float4 x0 = *reinterpret_cast<const float4*>(ap + ks * 32);
            float4 x1 = *reinterpret_cast<const float4*>(ap + ks * 32 + 4);
            split8(x0, x1, a_hi[ks], a_lo[ks]);
        }
    }

    // Online-softmax state: rows 4*kg + j (j=0..3), dims 16*col..+15.
    float m[4], l[4], msg[4][16];
#pragma unroll
    for (int j = 0; j < 4; ++j) {
        m[j] = -INFINITY; l[j] = 0.0f;
#pragma unroll
        for (int k = 0; k < 16; ++k) msg[j][k] = 0.0f;
    }

    for (int nt = n0; nt < n1; nt += 16) {
        const int  node  = nt + col;
        const bool valid = (node < n1);
        const int  nodec = node < NN ? node : NN - 1;
        const float* bp  = B + (size_t)nodec * DIM + kg * 8;

        floatx4 acc = {0.f, 0.f, 0.f, 0.f};
#pragma unroll
        for (int ks = 0; ks < 8; ++ks) {
            float4 b0 = *reinterpret_cast<const float4*>(bp + ks * 32);
            float4 b1 = *reinterpret_cast<const float4*>(bp + ks * 32 + 4);
            H8 bh, bl;
            split8(b0, b1, bh, bl);
            acc = __builtin_amdgcn_mfma_f32_16x16x32_f16(a_hi[ks].v8, bh.v8, acc, 0, 0, 0);
            acc = __builtin_amdgcn_mfma_f32_16x16x32_f16(a_lo[ks].v8, bh.v8, acc, 0, 0, 0);
            acc = __builtin_amdgcn_mfma_f32_16x16x32_f16(a_hi[ks].v8, bl.v8, acc, 0, 0, 0);
        }

        float e[4];
#pragma unroll
        for (int j = 0; j < 4; ++j) {
            float s  = valid ? acc[j] : -1e30f;
            float tm = s;
            tm = fmaxf(tm, __shfl_xor(tm, 1));
            tm = fmaxf(tm, __shfl_xor(tm, 2));
            tm = fmaxf(tm, __shfl_xor(tm, 4));
            tm = fmaxf(tm, __shfl_xor(tm, 8));
            if (tm > m[j]) {                       // rescale only on new max (rare)
                float sc = __expf((m[j] - tm) * INV_TAU);
                m[j] = tm;
                l[j] *= sc;
#pragma unroll
                for (int k = 0; k < 16; ++k) msg[j][k] *= sc;
            }
            float ej = __expf((s - m[j]) * INV_TAU);
            e[j] = ej;
            float es = ej;
            es += __shfl_xor(es, 1);
            es += __shfl_xor(es, 2);
            es += __shfl_xor(es, 4);
            es += __shfl_xor(es, 8);
            l[j] += es;
        }

        // Sparse PV: only nodes with non-negligible weight (~13 per row total).
#pragma unroll
        for (int j = 0; j < 4; ++j) {
            unsigned long long bal = __ballot(e[j] > THRESH);
            unsigned gm = (unsigned)((bal >> gbase) & 0xFFFFull);
            while (gm) {
                int src = __ffs(gm) - 1; gm &= gm - 1;
                float wgt = __shfl(e[j], gbase + src);
                const float* vp = B + (size_t)(nt + src) * DIM + col * 16;
                float4 v0 = *reinterpret_cast<const float4*>(vp + 0);
                float4 v1 = *reinterpret_cast<const float4*>(vp + 4);
                float4 v2 = *reinterpret_cast<const float4*>(vp + 8);
                float4 v3 = *reinterpret_cast<const float4*>(vp + 12);
                msg[j][0]  += wgt * v0.x; msg[j][1]  += wgt * v0.y; msg[j][2]  += wgt * v0.z; msg[j][3]  += wgt * v0.w;
                msg[j][4]  += wgt * v1.x; msg[j][5]  += wgt * v1.y; msg[j][6]  += wgt * v1.z; msg[j][7]  += wgt * v1.w;
                msg[j][8]  += wgt * v2.x; msg[j][9]  += wgt * v2.y; msg[j][10] += wgt * v2.z; msg[j][11] += wgt * v2.w;
                msg[j][12] += wgt * v3.x; msg[j][13] += wgt * v3.y; msg[j][14] += wgt * v3.z; msg[j][15] += wgt * v3.w;
            }
        }
    }

    // Epilogue: write partials.
#pragma unroll
    for (int j = 0; j < 4; ++j) {
        int row = wrow0 + 4 * kg + j;
        float* pr = part + ((size_t)ch * NP + row) * PSTR;
        if (col == 0) { pr[0] = m[j]; pr[1] = l[j]; }
        float4* pa = reinterpret_cast<float4*>(pr + 4 + col * 16);
        pa[0] = make_float4(msg[j][0],  msg[j][1],  msg[j][2],  msg[j][3]);
        pa[1] = make_float4(msg[j][4],  msg[j][5],  msg[j][6],  msg[j][7]);
        pa[2] = make_float4(msg[j][8],  msg[j][9],  msg[j][10], msg[j][11]);
        pa[3] = make_float4(msg[j][12], msg[j][13], msg[j][14], msg[j][15]);
    }
}

// ---------------------------------------------------------------------------
// K2: combine chunk partials -> messages -> updated = l2norm(patch + msg).
// One wave per row; lane owns 4 dims. Also writes evidence[row] = max sim.
// ---------------------------------------------------------------------------
__global__ __launch_bounds__(256)
void k_combine(const float* __restrict__ A, const float* __restrict__ part,
               float* __restrict__ out, float* __restrict__ evidence)
{
    const int w    = (int)threadIdx.x >> 6;
    const int lane = (int)threadIdx.x & 63;
    const int row  = blockIdx.x * 4 + w;
    const int d0   = lane * 4;

    float mc[NCH];
    float M = -INFINITY;
#pragma unroll
    for (int c = 0; c < NCH; ++c) {
        mc[c] = part[((size_t)c * NP + row) * PSTR];
        M = fmaxf(M, mc[c]);
    }
    float L = 0.0f;
    float mx = 0.f, my = 0.f, mz = 0.f, mw = 0.f;
#pragma unroll
    for (int c = 0; c < NCH; ++c) {
        const float* pr = part + ((size_t)c * NP + row) * PSTR;
        float wc = __expf((mc[c] - M) * INV_TAU);
        L += wc * pr[1];
        float4 a = *reinterpret_cast<const float4*>(pr + 4 + d0);
        mx += wc * a.x; my += wc * a.y; mz += wc * a.z; mw += wc * a.w;
    }
    float inv = 1.0f / L;
    float4 p = *reinterpret_cast<const float4*>(&A[(size_t)row * DIM + d0]);
    float ux = p.x + mx * inv, uy = p.y + my * inv;
    float uz = p.z + mz * inv, uw = p.w + mw * inv;
    float ss = ux * ux + uy * uy + uz * uz + uw * uw;
#pragma unroll
    for (int o = 1; o < 64; o <<= 1) ss += __shfl_xor(ss, o);
    float n = sqrtf(ss);
    float r = 1.0f / fmaxf(n, 1e-12f);
    *reinterpret_cast<float4*>(&out[256 + (size_t)row * DIM + d0]) =
        make_float4(ux * r, uy * r, uz * r, uw * r);
    if (lane == 0) evidence[row] = M;
}

// ---------------------------------------------------------------------------
// K3a: max of evidence (softmax denominator cancels under final l2norm).
// ---------------------------------------------------------------------------
__global__ __launch_bounds__(256)
void k_evmax(const float* __restrict__ evidence, float* __restrict__ me)
{
    __shared__ float red[256];
    int tid = (int)threadIdx.x;
    float M = -INFINITY;
    for (int r = tid; r < NP; r += 256) M = fmaxf(M, evidence[r]);
    red[tid] = M; __syncthreads();
    for (int s = 128; s > 0; s >>= 1) {
        if (tid < s) red[tid] = fmaxf(red[tid], red[tid + s]);
        __syncthreads();
    }
    if (tid == 0) me[0] = red[0];
}

// ---------------------------------------------------------------------------
// K3b: partial evidence-weighted sums of `updated` (16 blocks x 128 rows).
// ---------------------------------------------------------------------------
__global__ __launch_bounds__(256)
void k_gpart(const float* __restrict__ evidence, const float* __restrict__ me,
             const float* __restrict__ out, float* __restrict__ gpart)
{
    __shared__ float wsh[128];
    int tid = (int)threadIdx.x;
    int r0  = blockIdx.x * 128;
    float Me = me[0];
    if (tid < 128) wsh[tid] = __expf((evidence[r0 + tid] - Me) * INV_TAU);
    __syncthreads();
    float g = 0.0f;
    for (int k = 0; k < 128; ++k)
        g += wsh[k] * out[256 + (size_t)(r0 + k) * DIM + tid];
    gpart[blockIdx.x * 256 + tid] = g;
}

// ---------------------------------------------------------------------------
// K3c: reduce partials, l2-normalize, write global feature to out[0..255].
// ---------------------------------------------------------------------------
__global__ __launch_bounds__(256)
void k_final(const float* __restrict__ gpart, float* __restrict__ out)
{
    __shared__ float red[256];
    int tid = (int)threadIdx.x;
    float g = 0.0f;
#pragma unroll
    for (int b = 0; b < 16; ++b) g += gpart[b * 256 + tid];
    red[tid] = g * g; __syncthreads();
    for (int s = 128; s > 0; s >>= 1) {
        if (tid < s) red[tid] += red[tid + s];
        __syncthreads();
    }
    float n = sqrtf(red[0]);
    float r = 1.0f / fmaxf(n, 1e-12f);
    out[tid] = g * r;
}

// ---------------------------------------------------------------------------
extern "C" void kernel_launch(void* const* d_in, const int* in_sizes, int n_in,
                              void* d_out, int out_size, void* d_ws, size_t ws_size,
                              hipStream_t stream)
{
    const float* A = (const float*)d_in[0];   // test_patches 2048x256 f32
    const float* B = (const float*)d_in[1];   // memory_nodes 100000x256 f32
    float* out = (float*)d_out;               // [256 global] + [2048x256 updated]
    float* ws  = (float*)d_ws;

    float* part     = ws;                                   // NCH*NP*PSTR floats (~34 MB)
    float* evidence = ws + (size_t)NCH * NP * PSTR;         // NP floats
    float* me       = evidence + NP;                        // 1 float (+pad)
    float* gpart    = me + 16;                              // 16*256 floats

    k_attn   <<<dim3(16, NCH), 512, 0, stream>>>(A, B, part);
    k_combine<<<NP / 4,        256, 0, stream>>>(A, part, out, evidence);
    k_evmax  <<<1,             256, 0, stream>>>(evidence, me);
    k_gpart  <<<16,            256, 0, stream>>>(evidence, me, out, gpart);
    k_final  <<<1,             256, 0, stream>>>(gpart, out);
}

// Round 4
// 742.171 us; speedup vs baseline: 4.0716x; 1.9720x over previous
//
#include <hip/hip_runtime.h>
#include <cstdint>
#include <cstddef>

// Problem constants
#define NP      2048        // patches
#define NN      100000      // memory nodes
#define DIM     256
#define NT      6250        // 16-node tiles total (NN/16 exactly)
#define NCH     16          // node chunks
#define TPC     391         // tiles per chunk (last chunk gets 385)
#define RPB     128         // rows per k_attn block (8 waves x 16 rows)
#define INV_TAU 50.0f
#define THRESH  1e-12f
#define MARGIN  0.8f        // flag margin in sim units (need 0.553; f16 err 5sigma=0.026)
#define PSTR    260         // partial row stride: [m, l, pad, pad, acc[256]]

typedef __fp16 half8  __attribute__((ext_vector_type(8)));
typedef __fp16 half2v __attribute__((ext_vector_type(2)));
typedef float  floatx4 __attribute__((ext_vector_type(4)));

union H8 { half8 v8; half2v v2[4]; };

// ---------------------------------------------------------------------------
// k_convB: B (f32) -> fragment-major f16 RTZ array.
// Entry (t, ks, lane): node = 16t + (lane&15), dims d0 = (lane>>4)*8 + ks*32.
// One 512-thread block per tile: reads each B byte once, writes sequential.
// ---------------------------------------------------------------------------
__global__ __launch_bounds__(512)
void k_convB(const float* __restrict__ B, __fp16* __restrict__ Bh)
{
    const int t    = blockIdx.x;
    const int ks   = (int)threadIdx.x >> 6;
    const int lane = (int)threadIdx.x & 63;
    const int node = t * 16 + (lane & 15);
    const int d0   = (lane >> 4) * 8 + ks * 32;
    const float* bp = B + (size_t)node * DIM + d0;
    float4 b0 = *reinterpret_cast<const float4*>(bp);
    float4 b1 = *reinterpret_cast<const float4*>(bp + 4);
    H8 h;
    h.v2[0] = __builtin_amdgcn_cvt_pkrtz(b0.x, b0.y);
    h.v2[1] = __builtin_amdgcn_cvt_pkrtz(b0.z, b0.w);
    h.v2[2] = __builtin_amdgcn_cvt_pkrtz(b1.x, b1.y);
    h.v2[3] = __builtin_amdgcn_cvt_pkrtz(b1.z, b1.w);
    *reinterpret_cast<half8*>(Bh + ((size_t)(t * 8 + ks) * 64 + lane) * 8) = h.v8;
}

// ---------------------------------------------------------------------------
// k_attn: streaming online-softmax attention partials.
// QK^T: 1 MFMA per ks on f16-hi fragments; flagged nodes (s > m - MARGIN) get
// an exact f32 correction computed cooperatively by the 16-lane group from
// f32 A,B rows (L2-resident). Softmax update fully skipped for (tile,row)
// granules with empty flag ballot (~90%).
// ---------------------------------------------------------------------------
__global__ __launch_bounds__(512, 2)
void k_attn(const float* __restrict__ A, const float* __restrict__ B,
            const __fp16* __restrict__ Bh, float* __restrict__ part)
{
    const int tid   = (int)threadIdx.x;
    const int w     = tid >> 6;          // wave 0..7
    const int lane  = tid & 63;
    const int col   = lane & 15;         // node-in-tile
    const int kg    = lane >> 4;         // 0..3 k-group (row subgroup)
    const int gbase = lane & 48;
    const int wrow0 = blockIdx.x * RPB + w * 16;
    const int ch    = blockIdx.y;
    const int t0    = ch * TPC;
    const int t1    = (t0 + TPC < NT) ? (t0 + TPC) : NT;

    // Prologue: A hi-fragments (RTZ f16) for all 8 K-steps.
    H8 a_hi[8];
    {
        const float* ap = A + (size_t)(wrow0 + col) * DIM + kg * 8;
#pragma unroll
        for (int ks = 0; ks < 8; ++ks) {
            float4 x0 = *reinterpret_cast<const float4*>(ap + ks * 32);
            float4 x1 = *reinterpret_cast<const float4*>(ap + ks * 32 + 4);
            a_hi[ks].v2[0] = __builtin_amdgcn_cvt_pkrtz(x0.x, x0.y);
            a_hi[ks].v2[1] = __builtin_amdgcn_cvt_pkrtz(x0.z, x0.w);
            a_hi[ks].v2[2] = __builtin_amdgcn_cvt_pkrtz(x1.x, x1.y);
            a_hi[ks].v2[3] = __builtin_amdgcn_cvt_pkrtz(x1.z, x1.w);
        }
    }

    // Online-softmax state: row 4*kg + j, dims 16*col..+15.
    float m[4], l[4], msg[4][16];
#pragma unroll
    for (int j = 0; j < 4; ++j) {
        m[j] = -INFINITY; l[j] = 0.0f;
#pragma unroll
        for (int k = 0; k < 16; ++k) msg[j][k] = 0.0f;
    }

    const half8* bb = reinterpret_cast<const half8*>(Bh) + lane;

    auto LOADT = [&](half8 (&dst)[8], int tt) {
#pragma unroll
        for (int ks = 0; ks < 8; ++ks)
            dst[ks] = bb[(size_t)tt * 512 + ks * 64];
    };

    auto PROCESS = [&](const half8 (&bf)[8], int tt) {
        floatx4 acc = {0.f, 0.f, 0.f, 0.f};
#pragma unroll
        for (int ks = 0; ks < 8; ++ks)
            acc = __builtin_amdgcn_mfma_f32_16x16x32_f16(a_hi[ks].v8, bf[ks], acc, 0, 0, 0);
        const int nt = tt * 16;
#pragma unroll
        for (int j = 0; j < 4; ++j) {
            float sj = acc[j];
            unsigned long long bal = __ballot(sj > m[j] - MARGIN);
            unsigned gm = (unsigned)((bal >> gbase) & 0xFFFFull);
            if (gm) {
                const float* ap32 = A + (size_t)(wrow0 + 4 * kg + j) * DIM + col * 16;
                // exact corrections for flagged nodes
                unsigned cm = gm;
                while (cm) {
                    int src = __ffs(cm) - 1; cm &= cm - 1;
                    const float* bp32 = B + (size_t)(nt + src) * DIM + col * 16;
                    float corr = 0.f;
#pragma unroll
                    for (int q = 0; q < 4; ++q) {
                        float4 bv = *reinterpret_cast<const float4*>(bp32 + q * 4);
                        float4 av = *reinterpret_cast<const float4*>(ap32 + q * 4);
                        half2v bh01 = __builtin_amdgcn_cvt_pkrtz(bv.x, bv.y);
                        half2v bh23 = __builtin_amdgcn_cvt_pkrtz(bv.z, bv.w);
                        half2v ah01 = __builtin_amdgcn_cvt_pkrtz(av.x, av.y);
                        half2v ah23 = __builtin_amdgcn_cvt_pkrtz(av.z, av.w);
                        corr += av.x * bv.x - (float)ah01[0] * (float)bh01[0];
                        corr += av.y * bv.y - (float)ah01[1] * (float)bh01[1];
                        corr += av.z * bv.z - (float)ah23[0] * (float)bh23[0];
                        corr += av.w * bv.w - (float)ah23[1] * (float)bh23[1];
                    }
                    corr += __shfl_xor(corr, 1);
                    corr += __shfl_xor(corr, 2);
                    corr += __shfl_xor(corr, 4);
                    corr += __shfl_xor(corr, 8);
                    if (col == src) sj += corr;
                }
                // row max / rescale (rare)
                float tm = sj;
                tm = fmaxf(tm, __shfl_xor(tm, 1));
                tm = fmaxf(tm, __shfl_xor(tm, 2));
                tm = fmaxf(tm, __shfl_xor(tm, 4));
                tm = fmaxf(tm, __shfl_xor(tm, 8));
                if (tm > m[j]) {
                    float sc = __expf((m[j] - tm) * INV_TAU);
                    m[j] = tm; l[j] *= sc;
#pragma unroll
                    for (int k = 0; k < 16; ++k) msg[j][k] *= sc;
                }
                float ej = __expf((sj - m[j]) * INV_TAU);
                float es = ej;
                es += __shfl_xor(es, 1);
                es += __shfl_xor(es, 2);
                es += __shfl_xor(es, 4);
                es += __shfl_xor(es, 8);
                l[j] += es;
                // sparse PV
                unsigned long long bal2 = __ballot(ej > THRESH);
                unsigned pm = (unsigned)((bal2 >> gbase) & 0xFFFFull);
                while (pm) {
                    int src = __ffs(pm) - 1; pm &= pm - 1;
                    float wgt = __shfl(ej, gbase + src);
                    const float* vp = B + (size_t)(nt + src) * DIM + col * 16;
                    float4 v0 = *reinterpret_cast<const float4*>(vp + 0);
                    float4 v1 = *reinterpret_cast<const float4*>(vp + 4);
                    float4 v2 = *reinterpret_cast<const float4*>(vp + 8);
                    float4 v3 = *reinterpret_cast<const float4*>(vp + 12);
                    msg[j][0]  += wgt * v0.x; msg[j][1]  += wgt * v0.y; msg[j][2]  += wgt * v0.z; msg[j][3]  += wgt * v0.w;
                    msg[j][4]  += wgt * v1.x; msg[j][5]  += wgt * v1.y; msg[j][6]  += wgt * v1.z; msg[j][7]  += wgt * v1.w;
                    msg[j][8]  += wgt * v2.x; msg[j][9]  += wgt * v2.y; msg[j][10] += wgt * v2.z; msg[j][11] += wgt * v2.w;
                    msg[j][12] += wgt * v3.x; msg[j][13] += wgt * v3.y; msg[j][14] += wgt * v3.z; msg[j][15] += wgt * v3.w;
                }
            }
        }
    };

    // Double-buffered main loop.
    half8 bA[8], bB[8];
    LOADT(bA, t0);
    int t = t0;
    for (; t + 2 <= t1; t += 2) {
        LOADT(bB, t + 1);
        PROCESS(bA, t);
        if (t + 2 < t1) LOADT(bA, t + 2);
        PROCESS(bB, t + 1);
    }
    if (t < t1) PROCESS(bA, t);

    // Epilogue: write partials.
#pragma unroll
    for (int j = 0; j < 4; ++j) {
        int row = wrow0 + 4 * kg + j;
        float* pr = part + ((size_t)ch * NP + row) * PSTR;
        if (col == 0) { pr[0] = m[j]; pr[1] = l[j]; }
        float4* pa = reinterpret_cast<float4*>(pr + 4 + col * 16);
        pa[0] = make_float4(msg[j][0],  msg[j][1],  msg[j][2],  msg[j][3]);
        pa[1] = make_float4(msg[j][4],  msg[j][5],  msg[j][6],  msg[j][7]);
        pa[2] = make_float4(msg[j][8],  msg[j][9],  msg[j][10], msg[j][11]);
        pa[3] = make_float4(msg[j][12], msg[j][13], msg[j][14], msg[j][15]);
    }
}

// ---------------------------------------------------------------------------
// K2: combine chunk partials -> messages -> updated = l2norm(patch + msg).
// ---------------------------------------------------------------------------
__global__ __launch_bounds__(256)
void k_combine(const float* __restrict__ A, const float* __restrict__ part,
               float* __restrict__ out, float* __restrict__ evidence)
{
    const int w    = (int)threadIdx.x >> 6;
    const int lane = (int)threadIdx.x & 63;
    const int row  = blockIdx.x * 4 + w;
    const int d0   = lane * 4;

    float mc[NCH];
    float M = -INFINITY;
#pragma unroll
    for (int c = 0; c < NCH; ++c) {
        mc[c] = part[((size_t)c * NP + row) * PSTR];
        M = fmaxf(M, mc[c]);
    }
    float L = 0.0f;
    float mx = 0.f, my = 0.f, mz = 0.f, mw = 0.f;
#pragma unroll
    for (int c = 0; c < NCH; ++c) {
        const float* pr = part + ((size_t)c * NP + row) * PSTR;
        float wc = __expf((mc[c] - M) * INV_TAU);
        L += wc * pr[1];
        float4 a = *reinterpret_cast<const float4*>(pr + 4 + d0);
        mx += wc * a.x; my += wc * a.y; mz += wc * a.z; mw += wc * a.w;
    }
    float inv = 1.0f / L;
    float4 p = *reinterpret_cast<const float4*>(&A[(size_t)row * DIM + d0]);
    float ux = p.x + mx * inv, uy = p.y + my * inv;
    float uz = p.z + mz * inv, uw = p.w + mw * inv;
    float ss = ux * ux + uy * uy + uz * uz + uw * uw;
#pragma unroll
    for (int o = 1; o < 64; o <<= 1) ss += __shfl_xor(ss, o);
    float n = sqrtf(ss);
    float r = 1.0f / fmaxf(n, 1e-12f);
    *reinterpret_cast<float4*>(&out[256 + (size_t)row * DIM + d0]) =
        make_float4(ux * r, uy * r, uz * r, uw * r);
    if (lane == 0) evidence[row] = M;
}

// ---------------------------------------------------------------------------
// K3a: max of evidence (softmax denominator cancels under final l2norm).
// ---------------------------------------------------------------------------
__global__ __launch_bounds__(256)
void k_evmax(const float* __restrict__ evidence, float* __restrict__ me)
{
    __shared__ float red[256];
    int tid = (int)threadIdx.x;
    float M = -INFINITY;
    for (int r = tid; r < NP; r += 256) M = fmaxf(M, evidence[r]);
    red[tid] = M; __syncthreads();
    for (int s = 128; s > 0; s >>= 1) {
        if (tid < s) red[tid] = fmaxf(red[tid], red[tid + s]);
        __syncthreads();
    }
    if (tid == 0) me[0] = red[0];
}

// ---------------------------------------------------------------------------
// K3b: partial evidence-weighted sums of `updated` (16 blocks x 128 rows).
// ---------------------------------------------------------------------------
__global__ __launch_bounds__(256)
void k_gpart(const float* __restrict__ evidence, const float* __restrict__ me,
             const float* __restrict__ out, float* __restrict__ gpart)
{
    __shared__ float wsh[128];
    int tid = (int)threadIdx.x;
    int r0  = blockIdx.x * 128;
    float Me = me[0];
    if (tid < 128) wsh[tid] = __expf((evidence[r0 + tid] - Me) * INV_TAU);
    __syncthreads();
    float g = 0.0f;
    for (int k = 0; k < 128; ++k)
        g += wsh[k] * out[256 + (size_t)(r0 + k) * DIM + tid];
    gpart[blockIdx.x * 256 + tid] = g;
}

// ---------------------------------------------------------------------------
// K3c: reduce partials, l2-normalize, write global feature to out[0..255].
// ---------------------------------------------------------------------------
__global__ __launch_bounds__(256)
void k_final(const float* __restrict__ gpart, float* __restrict__ out)
{
    __shared__ float red[256];
    int tid = (int)threadIdx.x;
    float g = 0.0f;
#pragma unroll
    for (int b = 0; b < 16; ++b) g += gpart[b * 256 + tid];
    red[tid] = g * g; __syncthreads();
    for (int s = 128; s > 0; s >>= 1) {
        if (tid < s) red[tid] += red[tid + s];
        __syncthreads();
    }
    float n = sqrtf(red[0]);
    float r = 1.0f / fmaxf(n, 1e-12f);
    out[tid] = g * r;
}

// ---------------------------------------------------------------------------
extern "C" void kernel_launch(void* const* d_in, const int* in_sizes, int n_in,
                              void* d_out, int out_size, void* d_ws, size_t ws_size,
                              hipStream_t stream)
{
    const float* A = (const float*)d_in[0];   // test_patches 2048x256 f32
    const float* B = (const float*)d_in[1];   // memory_nodes 100000x256 f32
    float* out = (float*)d_out;               // [256 global] + [2048x256 updated]
    float* ws  = (float*)d_ws;

    // ws layout (floats):
    //   Bh frag   : NT*8*64*8 halves = 12,800,000 floats (51.2 MB)
    //   part      : NCH*NP*PSTR = 8,519,680 floats (34.1 MB)
    //   evidence  : NP
    //   me        : 16
    //   gpart     : 16*256
    __fp16* Bh      = (__fp16*)ws;
    float* part     = ws + (size_t)NT * 4096;
    float* evidence = part + (size_t)NCH * NP * PSTR;
    float* me       = evidence + NP;
    float* gpart    = me + 16;

    k_convB  <<<NT,            512, 0, stream>>>(B, Bh);
    k_attn   <<<dim3(NP / RPB, NCH), 512, 0, stream>>>(A, B, Bh, part);
    k_combine<<<NP / 4,        256, 0, stream>>>(A, part, out, evidence);
    k_evmax  <<<1,             256, 0, stream>>>(evidence, me);
    k_gpart  <<<16,            256, 0, stream>>>(evidence, me, out, gpart);
    k_final  <<<1,             256, 0, stream>>>(gpart, out);
}

// Round 5
// 231.287 us; speedup vs baseline: 13.0654x; 3.2089x over previous
//
#include <hip/hip_runtime.h>
#include <cstdint>
#include <cstddef>

// Problem constants
#define NP      2048        // patches
#define NN      100000      // memory nodes
#define DIM     256
#define NT      6250        // 16-node tiles (NN/16)
#define NG      1563        // 64-node granules = ceil(NT/4)
#define NGP     1568        // padded granule stride (float4 multiple)
#define NTP     (NG * 4)    // padded tiles = 6252
#define CPX     25          // granules per chunk (64 chunk slots, 63 used)
#define INV_TAU 50.0f
#define MARGIN  0.7f        // flag margin: need 0.553 (w=1e-12) + 2x f16-err bound
#define CUT     0.553f

typedef __fp16 half8  __attribute__((ext_vector_type(8)));
typedef __fp16 half2v __attribute__((ext_vector_type(2)));
typedef float  floatx4 __attribute__((ext_vector_type(4)));

union H8 { half8 v8; half2v v2[4]; };

typedef const __attribute__((address_space(1))) char* gptr_t;
typedef __attribute__((address_space(3))) char* sptr_t;

// ---------------------------------------------------------------------------
// k_convB: B (f32) -> fragment-major f16 RTZ array, zero-padded to NTP tiles.
// Entry (t, ks, lane): node = 16t + (lane&15), dims d = (lane>>4)*8 + ks*32 ..+8
// ---------------------------------------------------------------------------
__global__ __launch_bounds__(512)
void k_convB(const float* __restrict__ B, __fp16* __restrict__ Bh)
{
    const int t    = (int)blockIdx.x;
    const int ks   = (int)threadIdx.x >> 6;
    const int lane = (int)threadIdx.x & 63;
    H8 h;
    if (t < NT) {
        const int node = t * 16 + (lane & 15);
        const int d0   = ((lane >> 4) << 3) + (ks << 5);
        const float* bp = B + (size_t)node * DIM + d0;
        float4 b0 = *reinterpret_cast<const float4*>(bp);
        float4 b1 = *reinterpret_cast<const float4*>(bp + 4);
        h.v2[0] = __builtin_amdgcn_cvt_pkrtz(b0.x, b0.y);
        h.v2[1] = __builtin_amdgcn_cvt_pkrtz(b0.z, b0.w);
        h.v2[2] = __builtin_amdgcn_cvt_pkrtz(b1.x, b1.y);
        h.v2[3] = __builtin_amdgcn_cvt_pkrtz(b1.z, b1.w);
    } else {
        h.v2[0] = __builtin_amdgcn_cvt_pkrtz(0.f, 0.f);
        h.v2[1] = h.v2[0]; h.v2[2] = h.v2[0]; h.v2[3] = h.v2[0];
    }
    *reinterpret_cast<half8*>(Bh + (((size_t)t * 8 + ks) * 64 + lane) * 8) = h.v8;
}

// ---------------------------------------------------------------------------
// k_pass1: approx max-GEMM. Grid 256 blocks (8 xcd x 8 chunkslot x 4 rowblock),
// 512 threads = 8 waves, wave owns 64 rows (4 A-frag sets in registers).
// Swapped MFMA: mfma(B_frag, A_frag) -> D[node][patch], col=lane&15=patch.
// Per 64-node granule writes per-row max to tmax[row][g].
// ---------------------------------------------------------------------------
__global__ __launch_bounds__(512, 2)
void k_pass1(const float* __restrict__ A, const __fp16* __restrict__ Bh,
             float* __restrict__ tmax)
{
    __shared__ __fp16 lds[2][16384];   // 2 x 32 KB granule buffers

    const int tid  = (int)threadIdx.x;
    const int w    = tid >> 6;
    const int lane = tid & 63;
    const int col  = lane & 15;
    const int kg   = lane >> 4;

    const int bid   = (int)blockIdx.x;
    const int chunk = (bid & 7) * 8 + ((bid >> 3) & 7);   // XCD-pinned chunks
    const int rb    = (bid >> 6) & 3;

    const int g0 = chunk * CPX;
    if (g0 >= NG) return;
    const int g1 = (g0 + CPX < NG) ? g0 + CPX : NG;
    const int wrow0 = rb * 512 + w * 64;

    // A fragments: 4 rowsets x 8 ks (f16 RTZ), ~128 VGPR
    H8 af[4][8];
#pragma unroll
    for (int rs = 0; rs < 4; ++rs) {
        const float* ap = A + (size_t)(wrow0 + rs * 16 + col) * DIM + (kg << 3);
#pragma unroll
        for (int ks = 0; ks < 8; ++ks) {
            float4 x0 = *reinterpret_cast<const float4*>(ap + (ks << 5));
            float4 x1 = *reinterpret_cast<const float4*>(ap + (ks << 5) + 4);
            af[rs][ks].v2[0] = __builtin_amdgcn_cvt_pkrtz(x0.x, x0.y);
            af[rs][ks].v2[1] = __builtin_amdgcn_cvt_pkrtz(x0.z, x0.w);
            af[rs][ks].v2[2] = __builtin_amdgcn_cvt_pkrtz(x1.x, x1.y);
            af[rs][ks].v2[3] = __builtin_amdgcn_cvt_pkrtz(x1.z, x1.w);
        }
    }

    // Stage one 32 KB granule: wave w covers bytes [w*4K, w*4K+4K), 4 issues.
    auto STAGE = [&](int buf, int g) {
        const char* src = (const char*)Bh + ((size_t)g << 15) + (w << 12) + (lane << 4);
        char* dstb = (char*)&lds[buf][0] + (w << 12);
#pragma unroll
        for (int i = 0; i < 4; ++i)
            __builtin_amdgcn_global_load_lds((gptr_t)(src + (i << 10)),
                                             (sptr_t)(dstb + (i << 10)), 16, 0, 0);
    };

    STAGE(0, g0);
    int cur = 0;
    for (int g = g0; g < g1; ++g) {
        asm volatile("s_waitcnt vmcnt(0)" ::: "memory");
        __syncthreads();                       // buf[cur] staged for all waves
        if (g + 1 < g1) STAGE(cur ^ 1, g + 1); // prefetch next granule

        const __fp16* base = &lds[cur][0];
        float tm[4] = { -INFINITY, -INFINITY, -INFINITY, -INFINITY };
#pragma unroll
        for (int tt = 0; tt < 4; ++tt) {       // pad tiles are zero-filled: harmless
            floatx4 acc[4];
#pragma unroll
            for (int rs = 0; rs < 4; ++rs) acc[rs] = (floatx4){0.f, 0.f, 0.f, 0.f};
#pragma unroll
            for (int ks = 0; ks < 8; ++ks) {
                half8 bf = *reinterpret_cast<const half8*>(base + tt * 4096 + ks * 512 + lane * 8);
                acc[0] = __builtin_amdgcn_mfma_f32_16x16x32_f16(bf, af[0][ks].v8, acc[0], 0, 0, 0);
                acc[1] = __builtin_amdgcn_mfma_f32_16x16x32_f16(bf, af[1][ks].v8, acc[1], 0, 0, 0);
                acc[2] = __builtin_amdgcn_mfma_f32_16x16x32_f16(bf, af[2][ks].v8, acc[2], 0, 0, 0);
                acc[3] = __builtin_amdgcn_mfma_f32_16x16x32_f16(bf, af[3][ks].v8, acc[3], 0, 0, 0);
            }
#pragma unroll
            for (int rs = 0; rs < 4; ++rs)
                tm[rs] = fmaxf(tm[rs], fmaxf(fmaxf(acc[rs][0], acc[rs][1]),
                                             fmaxf(acc[rs][2], acc[rs][3])));
        }
        // reduce across the 4 kg groups (nodes 4kg+j of each tile)
#pragma unroll
        for (int rs = 0; rs < 4; ++rs) {
            tm[rs] = fmaxf(tm[rs], __shfl_xor(tm[rs], 16));
            tm[rs] = fmaxf(tm[rs], __shfl_xor(tm[rs], 32));
        }
        if (kg == 0) {
#pragma unroll
            for (int rs = 0; rs < 4; ++rs)
                tmax[(size_t)(wrow0 + rs * 16 + col) * NGP + g] = tm[rs];
        }
        __syncthreads();                       // all waves done reading buf[cur]
        cur ^= 1;
    }
}

// ---------------------------------------------------------------------------
// k_finish: one 256-thread block per row. Reduce granule maxes -> M; for
// flagged granules (tmax > M - MARGIN) recompute exact f32 sims, ordered
// online softmax + sparse PV; then updated = l2norm(A + msg/l), evidence = max.
// All branches are block-uniform; all summation orders deterministic.
// ---------------------------------------------------------------------------
__global__ __launch_bounds__(256)
void k_finish(const float* __restrict__ A, const float* __restrict__ B,
              const float* __restrict__ tmax, float* __restrict__ out,
              float* __restrict__ evidence)
{
    __shared__ float ald[256];
    __shared__ float tmx[NGP];
    __shared__ float sims[64];
    __shared__ float red[8];

    const int t    = (int)threadIdx.x;
    const int row  = (int)blockIdx.x;
    const int lane = t & 63;
    const int wv   = t >> 6;

    ald[t] = A[(size_t)row * DIM + t];

    const float* tr = tmax + (size_t)row * NGP;
    float M = -INFINITY;
    for (int i = t; i < NGP; i += 256) {
        float v = (i < NG) ? tr[i] : -INFINITY;
        tmx[i] = v;
        M = fmaxf(M, v);
    }
#pragma unroll
    for (int o = 1; o < 64; o <<= 1) M = fmaxf(M, __shfl_xor(M, o));
    if (lane == 0) red[wv] = M;
    __syncthreads();
    M = fmaxf(fmaxf(red[0], red[1]), fmaxf(red[2], red[3]));

    const float thr = M - MARGIN;
    float m = -INFINITY, l = 0.f, msg = 0.f;

    for (int q4 = 0; q4 < NGP / 4; ++q4) {
        float4 v = *reinterpret_cast<const float4*>(&tmx[q4 * 4]);
        if (fmaxf(fmaxf(v.x, v.y), fmaxf(v.z, v.w)) <= thr) continue;
#pragma unroll 1
        for (int jj = 0; jj < 4; ++jj) {
            float tv = (jj == 0) ? v.x : (jj == 1) ? v.y : (jj == 2) ? v.z : v.w;
            if (tv <= thr) continue;
            const int g  = q4 * 4 + jj;
            const int n0 = g * 64;
            const int count = (NN - n0 < 64) ? NN - n0 : 64;
            // exact f32 sims: thread t -> node t>>2, dim-quarter t&3
            {
                const int n = t >> 2, q = t & 3;
                float s = 0.f;
                if (n < count) {
                    const float4* bp = reinterpret_cast<const float4*>(B + (size_t)(n0 + n) * DIM + q * 64);
                    const float4* ap = reinterpret_cast<const float4*>(&ald[q * 64]);
#pragma unroll
                    for (int i = 0; i < 16; ++i) {
                        float4 b4 = bp[i], a4 = ap[i];
                        s += a4.x * b4.x + a4.y * b4.y + a4.z * b4.z + a4.w * b4.w;
                    }
                }
                s += __shfl_xor(s, 1);
                s += __shfl_xor(s, 2);
                __syncthreads();               // prior granule's sims reads done
                if ((t & 3) == 0 && (t >> 2) < count) sims[t >> 2] = s;
                __syncthreads();
            }
            float gm = -INFINITY;
            for (int i = 0; i < count; ++i) gm = fmaxf(gm, sims[i]);
            if (gm > m) {                       // block-uniform
                float sc = __expf((m - gm) * INV_TAU);
                m = gm; l *= sc; msg *= sc;
            }
            const float cut = m - CUT;
            for (int i = 0; i < count; ++i) {   // ordered, deterministic
                float si = sims[i];
                if (si > cut) {
                    float wn = __expf((si - m) * INV_TAU);
                    l += wn;
                    msg += wn * B[(size_t)(n0 + i) * DIM + t];
                }
            }
        }
    }

    float u = ald[t] + msg * (1.0f / l);
    float ss = u * u;
#pragma unroll
    for (int o = 1; o < 64; o <<= 1) ss += __shfl_xor(ss, o);
    if (lane == 0) red[4 + wv] = ss;
    __syncthreads();
    ss = (red[4] + red[5]) + (red[6] + red[7]);
    float rn = 1.0f / fmaxf(sqrtf(ss), 1e-12f);
    out[256 + (size_t)row * DIM + t] = u * rn;
    if (t == 0) evidence[row] = m;
}

// ---------------------------------------------------------------------------
// K3a: max of evidence (softmax denominator cancels under final l2norm).
// ---------------------------------------------------------------------------
__global__ __launch_bounds__(256)
void k_evmax(const float* __restrict__ evidence, float* __restrict__ me)
{
    __shared__ float red[256];
    int tid = (int)threadIdx.x;
    float M = -INFINITY;
    for (int r = tid; r < NP; r += 256) M = fmaxf(M, evidence[r]);
    red[tid] = M; __syncthreads();
    for (int s = 128; s > 0; s >>= 1) {
        if (tid < s) red[tid] = fmaxf(red[tid], red[tid + s]);
        __syncthreads();
    }
    if (tid == 0) me[0] = red[0];
}

// ---------------------------------------------------------------------------
// K3b: partial evidence-weighted sums of `updated` (16 blocks x 128 rows).
// ---------------------------------------------------------------------------
__global__ __launch_bounds__(256)
void k_gpart(const float* __restrict__ evidence, const float* __restrict__ me,
             const float* __restrict__ out, float* __restrict__ gpart)
{
    __shared__ float wsh[128];
    int tid = (int)threadIdx.x;
    int r0  = blockIdx.x * 128;
    float Me = me[0];
    if (tid < 128) wsh[tid] = __expf((evidence[r0 + tid] - Me) * INV_TAU);
    __syncthreads();
    float g = 0.0f;
    for (int k = 0; k < 128; ++k)
        g += wsh[k] * out[256 + (size_t)(r0 + k) * DIM + tid];
    gpart[blockIdx.x * 256 + tid] = g;
}

// ---------------------------------------------------------------------------
// K3c: reduce partials, l2-normalize, write global feature to out[0..255].
// ---------------------------------------------------------------------------
__global__ __launch_bounds__(256)
void k_final(const float* __restrict__ gpart, float* __restrict__ out)
{
    __shared__ float red[256];
    int tid = (int)threadIdx.x;
    float g = 0.0f;
#pragma unroll
    for (int b = 0; b < 16; ++b) g += gpart[b * 256 + tid];
    red[tid] = g * g; __syncthreads();
    for (int s = 128; s > 0; s >>= 1) {
        if (tid < s) red[tid] += red[tid + s];
        __syncthreads();
    }
    float n = sqrtf(red[0]);
    float r = 1.0f / fmaxf(n, 1e-12f);
    out[tid] = g * r;
}

// ---------------------------------------------------------------------------
extern "C" void kernel_launch(void* const* d_in, const int* in_sizes, int n_in,
                              void* d_out, int out_size, void* d_ws, size_t ws_size,
                              hipStream_t stream)
{
    const float* A = (const float*)d_in[0];   // test_patches 2048x256 f32
    const float* B = (const float*)d_in[1];   // memory_nodes 100000x256 f32
    float* out = (float*)d_out;               // [256 global] + [2048x256 updated]
    float* ws  = (float*)d_ws;

    // ws layout (floats):
    //   Bh   : NTP*4096 halves = NTP*2048 floats (51.2 MB)
    //   tmax : 2048*NGP (12.85 MB)
    //   evidence: 2048; me: 16; gpart: 4096
    __fp16* Bh      = (__fp16*)ws;
    float* tmaxp    = ws + (size_t)NTP * 2048;
    float* evidence = tmaxp + (size_t)NP * NGP;
    float* me       = evidence + NP;
    float* gpart    = me + 16;

    k_convB <<<NTP,  512, 0, stream>>>(B, Bh);
    k_pass1 <<<256,  512, 0, stream>>>(A, Bh, tmaxp);
    k_finish<<<NP,   256, 0, stream>>>(A, B, tmaxp, out, evidence);
    k_evmax <<<1,    256, 0, stream>>>(evidence, me);
    k_gpart <<<16,   256, 0, stream>>>(evidence, me, out, gpart);
    k_final <<<1,    256, 0, stream>>>(gpart, out);
}